// Round 8
// baseline (161.820 us; speedup 1.0000x reference)
//
#include <hip/hip_runtime.h>
#include <hip/hip_bf16.h>

#define B_DIM 8192
#define D_DIM 256
#define GRID_GEMM 1024
#define NT 16   // 32-col panels per block (512 cols per block)

constexpr float INV_T = 14.285714285714286f;   // 1/0.07; also the logsumexp shift M

typedef __bf16 bf16x8 __attribute__((ext_vector_type(8)));
typedef float  f32x16 __attribute__((ext_vector_type(16)));

__device__ inline unsigned short f2bf(float f) {
    union { float f; unsigned u; } x; x.f = f;
    unsigned r = x.u + 0x7fffu + ((x.u >> 16) & 1u);  // RNE
    return (unsigned short)(r >> 16);
}

// Kernel 1: panel-transpose normalize. One 32-row panel per block (512 blocks:
// p<256 -> q panel p from h+r; else t panel p-256). Stages the fp32 panel in
// LDS (row stride 257 f32 -> 2-way bank conflicts only), computes row norms,
// then writes the bf16 swizzled-fragment layout with CONTIGUOUS 16B stores
// (R7's norm scattered 8B granules -> ~35 us wall; this is fully coalesced).
// Swizzled layout (unchanged from R7): byte = panel*16384 + chunk*512 + (row&31)*16.
__global__ __launch_bounds__(256) void norm_kernel(
    const float* __restrict__ h, const float* __restrict__ r,
    const float* __restrict__ t,
    unsigned short* __restrict__ qws, unsigned short* __restrict__ tws)
{
    __shared__ float lds[32 * 257];
    __shared__ float part[32 * 9];
    __shared__ float scale[32];

    const int tid = threadIdx.x;
    const int p   = blockIdx.x;
    const bool isQ = p < 256;
    const int prow = (isQ ? p : p - 256) * 32;   // first global row of panel

    // ---- stage panel: 32 rows x 64 float4 (coalesced) ----
    const float4* h4 = (const float4*)h;
    const float4* r4 = (const float4*)r;
    const float4* t4 = (const float4*)t;
#pragma unroll
    for (int j = 0; j < 8; ++j) {
        int idx = j * 256 + tid;           // float4 index in panel
        int rl = idx >> 6, c4 = idx & 63;
        float4 v;
        if (isQ) {
            float4 a = h4[(prow + rl) * 64 + c4];
            float4 b = r4[(prow + rl) * 64 + c4];
            v = make_float4(a.x + b.x, a.y + b.y, a.z + b.z, a.w + b.w);
        } else {
            v = t4[(prow + rl) * 64 + c4];
        }
        float* d = &lds[rl * 257 + c4 * 4];
        d[0] = v.x; d[1] = v.y; d[2] = v.z; d[3] = v.w;
    }
    __syncthreads();

    // ---- row partial sums: lane pattern (rl = tid&31) -> 2-way conflicts ----
    {
        int rl = tid & 31, p8 = tid >> 5;
        const float* src = &lds[rl * 257 + p8 * 32];
        float s = 0.f;
#pragma unroll
        for (int k = 0; k < 32; ++k) { float x = src[k]; s += x * x; }
        part[rl * 9 + p8] = s;
    }
    __syncthreads();
    if (tid < 32) {
        float s = 0.f;
#pragma unroll
        for (int k = 0; k < 8; ++k) s += part[tid * 9 + k];
        scale[tid] = 1.0f / fmaxf(sqrtf(s), 1e-12f);
    }
    __syncthreads();

    // ---- write swizzled bf16: 1024 chunks of 16B, contiguous stores ----
    uint4* dst = (uint4*)((isQ ? qws : tws)) + (size_t)(isQ ? p : p - 256) * 1024;
#pragma unroll
    for (int j = 0; j < 4; ++j) {
        int id = j * 256 + tid;
        int c = id >> 5, rl = id & 31;
        float sc = scale[rl];
        const float* src = &lds[rl * 257 + c * 8];
        unsigned e0 = f2bf(src[0] * sc) | ((unsigned)f2bf(src[1] * sc) << 16);
        unsigned e1 = f2bf(src[2] * sc) | ((unsigned)f2bf(src[3] * sc) << 16);
        unsigned e2 = f2bf(src[4] * sc) | ((unsigned)f2bf(src[5] * sc) << 16);
        unsigned e3 = f2bf(src[6] * sc) | ((unsigned)f2bf(src[7] * sc) << 16);
        dst[c * 32 + rl] = make_uint4(e0, e1, e2, e3);   // byte: c*512 + rl*16
    }
}

// Kernel 2: LDS-free streaming GEMM, 32x32 wave tiles for occupancy + deep
// load pipelining. Grid 1024 = 64 row-blocks x 16 col-chunks (cc fast ->
// XCD L2 locality; 4 waves/block read identical B panels -> L1 reuse).
// Wave = 32 rows x 32 cols, A (32 rows x K=256) in 64 VGPRs; mandatory regs
// ~111 so launch_bounds(256,3) leaves ~50 regs for ~12-deep b prefetch and
// gives 3 waves/SIMD (vs R7's register-starved 2 with 1-2 loads in flight).
__global__ __launch_bounds__(256, 3) void gemm_lse_kernel(
    const unsigned char* __restrict__ qws, const unsigned char* __restrict__ tws,
    float* __restrict__ rowsum, float* __restrict__ diagsum,
    int* __restrict__ ticket, float* __restrict__ out)
{
    __shared__ float wred[4];
    __shared__ int lastflag;

    const int tid  = threadIdx.x;
    const int lane = tid & 63;
    const int w    = tid >> 6;
    const int l31  = lane & 31;
    const int hi   = lane >> 5;

    const int cc   = blockIdx.x & 15;        // col chunk (fast -> XCD locality)
    const int rb   = blockIdx.x >> 4;        // row block 0..63
    const int row0 = rb * 128 + w * 32;      // this wave's 32 rows
    const int col0 = cc * 512;

    // A fragments: a[ks] = qws[panel(row0>>5)][chunk ks*2+hi][l31]
    bf16x8 a[16];
    {
        const bf16x8* qa = (const bf16x8*)qws;
        const int pofs = (row0 >> 5) * 1024 + hi * 32 + l31;
#pragma unroll
        for (int ks = 0; ks < 16; ++ks)
            a[ks] = qa[pofs + ks * 64];
    }

    f32x16 rowacc = {};
    float diagacc = 0.f;
    const bf16x8* tb = (const bf16x8*)tws;

    for (int nt = 0; nt < NT; ++nt) {
        const int bofs = ((col0 >> 5) + nt) * 1024 + hi * 32 + l31;
        f32x16 acc = {};
#pragma unroll
        for (int ks = 0; ks < 16; ++ks) {
            bf16x8 b = tb[bofs + ks * 64];   // contiguous 1KB wave load
            acc = __builtin_amdgcn_mfma_f32_32x32x16_bf16(a[ks], b, acc, 0, 0, 0);
        }

#pragma unroll
        for (int g = 0; g < 16; ++g)
            rowacc[g] += __expf(fmaf(acc[g], INV_T, -INV_T));

        // diagonal tile: wave-uniform, at most 1 of 16 iterations
        if (col0 + nt * 32 == row0) {
#pragma unroll
            for (int g = 0; g < 16; ++g) {
                int rm = (g & 3) + 8 * (g >> 2) + 4 * hi;
                if (l31 == rm) diagacc += acc[g] * INV_T;
            }
        }
    }

    // reduce across the 32 column-lanes (per hi half), then atomics
#pragma unroll
    for (int g = 0; g < 16; ++g) {
        float s = rowacc[g];
        s += __shfl_xor(s, 1, 64);
        s += __shfl_xor(s, 2, 64);
        s += __shfl_xor(s, 4, 64);
        s += __shfl_xor(s, 8, 64);
        s += __shfl_xor(s, 16, 64);
        if (l31 == 0) {
            int grow = row0 + (g & 3) + 8 * (g >> 2) + 4 * hi;
            atomicAdd(&rowsum[grow], s);
        }
    }

    float dsum = diagacc;
#pragma unroll
    for (int off = 32; off; off >>= 1) dsum += __shfl_xor(dsum, off, 64);
    if (lane == 0 && dsum != 0.f) atomicAdd(diagsum, dsum);

    // ticket: last block computes the loss
    __syncthreads();
    if (tid == 0) {
        __threadfence();
        int old = __hip_atomic_fetch_add(ticket, 1, __ATOMIC_ACQ_REL,
                                         __HIP_MEMORY_SCOPE_AGENT);
        lastflag = (old == GRID_GEMM - 1);
    }
    __syncthreads();
    if (!lastflag) return;

    float lsum = 0.f;
    for (int rr = tid; rr < B_DIM; rr += 256) {
        float rs = __hip_atomic_load(&rowsum[rr], __ATOMIC_RELAXED,
                                     __HIP_MEMORY_SCOPE_AGENT);
        lsum += __logf(rs);
    }
#pragma unroll
    for (int off = 32; off; off >>= 1) lsum += __shfl_xor(lsum, off, 64);
    if (lane == 0) wred[w] = lsum;
    __syncthreads();
    if (tid == 0) {
        float ds = __hip_atomic_load(diagsum, __ATOMIC_RELAXED,
                                     __HIP_MEMORY_SCOPE_AGENT);
        float total = wred[0] + wred[1] + wred[2] + wred[3]
                    + (float)B_DIM * INV_T   // + M per row
                    - ds;                    // - positive logits
        out[0] = total / (float)B_DIM;
    }
}

extern "C" void kernel_launch(void* const* d_in, const int* in_sizes, int n_in,
                              void* d_out, int out_size, void* d_ws, size_t ws_size,
                              hipStream_t stream)
{
    const float* h = (const float*)d_in[0];
    const float* r = (const float*)d_in[1];
    const float* t = (const float*)d_in[2];

    unsigned char* ws = (unsigned char*)d_ws;
    unsigned short* qws = (unsigned short*)ws;                        // 4 MB
    unsigned short* tws = (unsigned short*)(ws + 4u * 1024 * 1024);   // 4 MB
    float* rowsum  = (float*)(ws + 8u * 1024 * 1024);                 // 32 KB
    float* diagsum = (float*)(ws + 8u * 1024 * 1024 + 32768u);
    int*   ticket  = (int*)  (ws + 8u * 1024 * 1024 + 32768u + 4);

    // zero rowsum + diagsum + ticket
    hipMemsetAsync(ws + 8u * 1024 * 1024, 0, 32768u + 16, stream);

    norm_kernel<<<512, 256, 0, stream>>>(h, r, t, qws, tws);
    gemm_lse_kernel<<<GRID_GEMM, 256, 0, stream>>>(
        (const unsigned char*)qws, (const unsigned char*)tws,
        rowsum, diagsum, ticket, (float*)d_out);
}

// Round 9
// 144.988 us; speedup vs baseline: 1.1161x; 1.1161x over previous
//
#include <hip/hip_runtime.h>
#include <hip/hip_bf16.h>

#define B_DIM 8192
#define D_DIM 256
#define GRID_GEMM 512
#define NT 8   // 64-col tiles per block (512 cols per block)

constexpr float INV_T = 14.285714285714286f;   // 1/0.07; also the logsumexp shift M

typedef __bf16 bf16x8 __attribute__((ext_vector_type(8)));
typedef float  f32x4  __attribute__((ext_vector_type(4)));

#define GLOBAL_U32(p) ((const __attribute__((address_space(1))) unsigned int*)(p))
#define LDS_U32(p)    ((__attribute__((address_space(3))) unsigned int*)(p))

// s_waitcnt imm: vm[3:0]=bits3:0, exp=bits6:4, lgkm=bits11:8, vm[5:4]=bits15:14
#define WAITCNT_VM0 0x0F70   // vmcnt(0), exp/lgkm no-wait

__device__ inline unsigned short f2bf(float f) {
    union { float f; unsigned u; } x; x.f = f;
    unsigned r = x.u + 0x7fffu + ((x.u >> 16) & 1u);  // RNE
    return (unsigned short)(r >> 16);
}

// Kernel 1 (R5's proven version): q = normalize(h+r), t = normalize(t) ->
// bf16 row-major workspace. Block 0 zeroes rowsum/diagsum/ticket (no memset
// dispatch needed).
__global__ __launch_bounds__(256) void norm_kernel(
    const float* __restrict__ h, const float* __restrict__ r,
    const float* __restrict__ t,
    unsigned short* __restrict__ qws, unsigned short* __restrict__ tws,
    float* __restrict__ rowsum, float* __restrict__ diagsum, int* __restrict__ ticket)
{
    if (blockIdx.x == 0) {
        float4* rs4 = (float4*)rowsum;
#pragma unroll
        for (int i = 0; i < 8; ++i)
            rs4[threadIdx.x * 8 + i] = make_float4(0.f, 0.f, 0.f, 0.f);
        if (threadIdx.x == 0) { *diagsum = 0.f; *ticket = 0; }
    }

    int wave = threadIdx.x >> 6;
    int lane = threadIdx.x & 63;
    int task = blockIdx.x * 4 + wave;
    bool isQ = task < B_DIM;
    int row  = isQ ? task : task - B_DIM;

    float4 v;
    if (isQ) {
        float4 a = ((const float4*)h)[row * 64 + lane];
        float4 b = ((const float4*)r)[row * 64 + lane];
        v = make_float4(a.x + b.x, a.y + b.y, a.z + b.z, a.w + b.w);
    } else {
        v = ((const float4*)t)[row * 64 + lane];
    }
    float s = v.x * v.x + v.y * v.y + v.z * v.z + v.w * v.w;
#pragma unroll
    for (int off = 32; off; off >>= 1) s += __shfl_xor(s, off, 64);
    float scale = 1.0f / fmaxf(sqrtf(s), 1e-12f);

    ushort4 o;
    o.x = f2bf(v.x * scale);
    o.y = f2bf(v.y * scale);
    o.z = f2bf(v.z * scale);
    o.w = f2bf(v.w * scale);
    ushort4* dst = (ushort4*)(isQ ? qws : tws);
    dst[row * 64 + lane] = o;
}

// Kernel 2: A-in-registers GEMM with SINGLE-BARRIER double buffer and fat
// 64-col tiles (NT=8 iterations — halves the per-barrier-iteration fixed
// tax identified across R1/R3/R4/R5). Wave = 64 rows x 64 cols via
// mfma_f32_16x16x32_bf16, 4x4 accumulator grid (16 independent chains,
// 1 ds_read_b128 : 4 MFMA). Iteration: waitcnt(stage nt) -> barrier ->
// issue stage(nt+1) [post-barrier: overwritten buffer's readers provably
// done; the wait for it happens one full compute-phase later] -> compute.
// B LDS XOR-swizzled (phys chunk = kc ^ (n&7)): global_load_lds-legal,
// 2-way (free) conflicts on frag reads.
__global__ __launch_bounds__(256) void gemm_lse_kernel(
    const unsigned char* __restrict__ qws, const unsigned char* __restrict__ tws,
    float* __restrict__ rowsum, float* __restrict__ diagsum,
    int* __restrict__ ticket, float* __restrict__ out)
{
    __shared__ __align__(16) unsigned char ldsB[2][64 * 512];   // 64 KB
    __shared__ float wred[4];
    __shared__ int lastflag;

    const int tid  = threadIdx.x;
    const int lane = tid & 63;
    const int w    = tid >> 6;
    const int quad = lane >> 4;
    const int l15  = lane & 15;

    const int cc   = blockIdx.x & 15;        // col chunk
    const int rb   = blockIdx.x >> 4;        // row block 0..31
    const int row0 = rb * 256 + w * 64;      // this wave's 64 rows
    const int col0 = cc * 512;

    // staging map: slot s = it*256+tid -> col n = s>>5, phys chunk p = s&31,
    // logical chunk kc = p ^ (n&7); global ofs = n*512 + kc*16
    int srel[8];
#pragma unroll
    for (int it = 0; it < 8; ++it) {
        int s = it * 256 + tid;
        int n = s >> 5;
        int kc = (s & 31) ^ (n & 7);
        srel[it] = n * 512 + kc * 16;
    }

    // stage tile snt (64 cols x 512 B = 32 KB) into buffer bufi
#define STAGE(snt, bufi)                                                     \
    {                                                                        \
        const unsigned char* gs = tws + (size_t)(col0 + (snt) * 64) * 512;   \
        _Pragma("unroll")                                                    \
        for (int it = 0; it < 8; ++it)                                       \
            __builtin_amdgcn_global_load_lds(                                \
                GLOBAL_U32(gs + srel[it]),                                   \
                LDS_U32(&ldsB[bufi][(it * 256 + tid) * 16]), 16, 0, 0);      \
    }

    STAGE(0, 0);

    // A fragments in registers: rows row0..row0+63, full K=256.
    // 16x16x32 A layout: m = l15, k = ks*32 + quad*8 + j -> 16B contiguous
    bf16x8 a[4][8];
#pragma unroll
    for (int rt = 0; rt < 4; ++rt) {
        const unsigned char* base =
            qws + (size_t)(row0 + rt * 16 + l15) * 512 + quad * 16;
#pragma unroll
        for (int ks = 0; ks < 8; ++ks)
            a[rt][ks] = *(const bf16x8*)(base + ks * 64);
    }

    float rowacc[4][4];
#pragma unroll
    for (int rt = 0; rt < 4; ++rt)
#pragma unroll
        for (int i = 0; i < 4; ++i) rowacc[rt][i] = 0.f;
    float diagacc = 0.f;

    for (int nt = 0; nt < NT; ++nt) {
        // stage(nt) landed (per-wave; issued one full compute-phase ago)
        __builtin_amdgcn_s_waitcnt(WAITCNT_VM0);
        // all waves: stage(nt) landed AND compute(nt-1) finished
        __builtin_amdgcn_s_barrier();
        // overwrites tile nt-1's buffer -- safe post-barrier
        if (nt + 1 < NT) STAGE(nt + 1, (nt + 1) & 1);

        const unsigned char* bbuf = ldsB[nt & 1];
        f32x4 acc[4][4];
#pragma unroll
        for (int rt = 0; rt < 4; ++rt)
#pragma unroll
            for (int ct = 0; ct < 4; ++ct)
                acc[rt][ct] = f32x4{0.f, 0.f, 0.f, 0.f};

#pragma unroll
        for (int ks = 0; ks < 8; ++ks) {
            bf16x8 b[4];
#pragma unroll
            for (int ct = 0; ct < 4; ++ct) {
                int n = ct * 16 + l15;
                b[ct] = *(const bf16x8*)(bbuf + n * 512 +
                                         (((ks * 4 + quad) ^ (n & 7)) * 16));
            }
#pragma unroll
            for (int rt = 0; rt < 4; ++rt)
#pragma unroll
                for (int ct = 0; ct < 4; ++ct)
                    acc[rt][ct] = __builtin_amdgcn_mfma_f32_16x16x32_bf16(
                        a[rt][ks], b[ct], acc[rt][ct], 0, 0, 0);
        }

        // epilogue: exp-sum per row; diagonal (wave-uniform branch per tile)
#pragma unroll
        for (int rt = 0; rt < 4; ++rt) {
#pragma unroll
            for (int ct = 0; ct < 4; ++ct) {
                const bool isdiag =
                    (row0 + rt * 16) == (col0 + nt * 64 + ct * 16);
#pragma unroll
                for (int i = 0; i < 4; ++i) {
                    float d = acc[rt][ct][i];
                    rowacc[rt][i] += __expf(fmaf(d, INV_T, -INV_T));
                    if (isdiag && l15 == quad * 4 + i)
                        diagacc += d * INV_T;
                }
            }
        }
    }

    // once per block: reduce row partials across the 16 l15 lanes -> atomics
#pragma unroll
    for (int rt = 0; rt < 4; ++rt)
#pragma unroll
        for (int i = 0; i < 4; ++i) {
            float s = rowacc[rt][i];
            s += __shfl_xor(s, 1, 64);
            s += __shfl_xor(s, 2, 64);
            s += __shfl_xor(s, 4, 64);
            s += __shfl_xor(s, 8, 64);
            if (l15 == 0)
                atomicAdd(&rowsum[row0 + rt * 16 + quad * 4 + i], s);
        }

    float dsum = diagacc;
#pragma unroll
    for (int off = 32; off; off >>= 1) dsum += __shfl_xor(dsum, off, 64);
    if (lane == 0 && dsum != 0.f) atomicAdd(diagsum, dsum);

    // ticket: last block computes the loss
    __syncthreads();
    if (tid == 0) {
        __threadfence();
        int old = __hip_atomic_fetch_add(ticket, 1, __ATOMIC_ACQ_REL,
                                         __HIP_MEMORY_SCOPE_AGENT);
        lastflag = (old == GRID_GEMM - 1);
    }
    __syncthreads();
    if (!lastflag) return;

    float lsum = 0.f;
    for (int rr = tid; rr < B_DIM; rr += 256) {
        float rs = __hip_atomic_load(&rowsum[rr], __ATOMIC_RELAXED,
                                     __HIP_MEMORY_SCOPE_AGENT);
        lsum += __logf(rs);
    }
#pragma unroll
    for (int off = 32; off; off >>= 1) lsum += __shfl_xor(lsum, off, 64);
    if (lane == 0) wred[w] = lsum;
    __syncthreads();
    if (tid == 0) {
        float ds = __hip_atomic_load(diagsum, __ATOMIC_RELAXED,
                                     __HIP_MEMORY_SCOPE_AGENT);
        float total = wred[0] + wred[1] + wred[2] + wred[3]
                    + (float)B_DIM * INV_T   // + M per row
                    - ds;                    // - positive logits
        out[0] = total / (float)B_DIM;
    }
}

extern "C" void kernel_launch(void* const* d_in, const int* in_sizes, int n_in,
                              void* d_out, int out_size, void* d_ws, size_t ws_size,
                              hipStream_t stream)
{
    const float* h = (const float*)d_in[0];
    const float* r = (const float*)d_in[1];
    const float* t = (const float*)d_in[2];

    unsigned char* ws = (unsigned char*)d_ws;
    unsigned short* qws = (unsigned short*)ws;                        // 4 MB
    unsigned short* tws = (unsigned short*)(ws + 4u * 1024 * 1024);   // 4 MB
    float* rowsum  = (float*)(ws + 8u * 1024 * 1024);                 // 32 KB
    float* diagsum = (float*)(ws + 8u * 1024 * 1024 + 32768u);
    int*   ticket  = (int*)  (ws + 8u * 1024 * 1024 + 32768u + 4);

    norm_kernel<<<4096, 256, 0, stream>>>(h, r, t, qws, tws, rowsum, diagsum, ticket);
    gemm_lse_kernel<<<GRID_GEMM, 256, 0, stream>>>(
        (const unsigned char*)qws, (const unsigned char*)tws,
        rowsum, diagsum, ticket, (float*)d_out);
}

// Round 10
// 144.549 us; speedup vs baseline: 1.1195x; 1.0030x over previous
//
#include <hip/hip_runtime.h>
#include <hip/hip_bf16.h>

#define B_DIM 8192
#define D_DIM 256
#define GRID_GEMM 512

constexpr float INV_T = 14.285714285714286f;   // 1/0.07; also the logsumexp shift M
constexpr float K2    = 20.609375233857048f;   // INV_T * log2(e), for exp2-based exp

typedef float f32x4 __attribute__((ext_vector_type(4)));

// Kernel 1: q = normalize(h+r), t = normalize(t) -> fp8 e4m3 row-major ws.
// One wave per row; lane l writes bytes [4l,4l+4) of the 256 B row (coalesced).
// Block 0 zeroes rowsum/diagsum/ticket.
__global__ __launch_bounds__(256) void norm_kernel(
    const float* __restrict__ h, const float* __restrict__ r,
    const float* __restrict__ t,
    unsigned int* __restrict__ qws, unsigned int* __restrict__ tws,
    float* __restrict__ rowsum, float* __restrict__ diagsum, int* __restrict__ ticket)
{
    if (blockIdx.x == 0) {
        float4* rs4 = (float4*)rowsum;
#pragma unroll
        for (int i = 0; i < 8; ++i)
            rs4[threadIdx.x * 8 + i] = make_float4(0.f, 0.f, 0.f, 0.f);
        if (threadIdx.x == 0) { *diagsum = 0.f; *ticket = 0; }
    }

    int wave = threadIdx.x >> 6;
    int lane = threadIdx.x & 63;
    int task = blockIdx.x * 4 + wave;
    bool isQ = task < B_DIM;
    int row  = isQ ? task : task - B_DIM;

    float4 v;
    if (isQ) {
        float4 a = ((const float4*)h)[row * 64 + lane];
        float4 b = ((const float4*)r)[row * 64 + lane];
        v = make_float4(a.x + b.x, a.y + b.y, a.z + b.z, a.w + b.w);
    } else {
        v = ((const float4*)t)[row * 64 + lane];
    }
    float s = v.x * v.x + v.y * v.y + v.z * v.z + v.w * v.w;
#pragma unroll
    for (int off = 32; off; off >>= 1) s += __shfl_xor(s, off, 64);
    float scale = 1.0f / fmaxf(sqrtf(s), 1e-12f);

    // pack 4 fp8 e4m3 into one dword (OCP format on gfx950)
    unsigned lo = __builtin_amdgcn_cvt_pk_fp8_f32(v.x * scale, v.y * scale, 0, false);
    unsigned hi = __builtin_amdgcn_cvt_pk_fp8_f32(v.z * scale, v.w * scale, 0, false);
    (isQ ? qws : tws)[row * 64 + lane] = (lo & 0xffffu) | (hi << 16);
}

// Kernel 2: byte-minimal direct-load fp8 GEMM. No LDS, no barriers in the
// main loop — waves free-run at the measured ~10 B/cyc/CU global-load
// ceiling (the binding resource identified across R1-R9).
// Grid 512 = 16 row-sets x 32 col-chunks; block = 4 waves = 4 row-groups of
// 128 rows, all sharing one 256-col chunk (L1 reuse of B frags).
// Wave = 128 rows x 16-col strips: A (128 rows x K=256 fp8 = 32 KB) in 128
// VGPRs loaded once; per strip: 8 x 8B B-frag loads feed 64 MFMAs
// (mfma_f32_16x16x32_fp8_fp8, 8 row-tiles x 8 k-steps). Logical global
// traffic: B 128 MB + A 64 MB (fp8) vs R7's 512 MB bf16.
__global__ __launch_bounds__(256, 2) void gemm_lse_kernel(
    const unsigned char* __restrict__ qws, const unsigned char* __restrict__ tws,
    float* __restrict__ rowsum, float* __restrict__ diagsum,
    int* __restrict__ ticket, float* __restrict__ out)
{
    __shared__ float wred[4];
    __shared__ int lastflag;

    const int tid  = threadIdx.x;
    const int lane = tid & 63;
    const int w    = tid >> 6;
    const int quad = lane >> 4;
    const int l15  = lane & 15;

    const int cc   = blockIdx.x & 31;          // col chunk (256 cols)
    const int rs   = blockIdx.x >> 5;          // row set 0..15
    const int row0 = (rs * 4 + w) * 128;       // this wave's 128 rows
    const int col0 = cc * 256;

    const long* qa = (const long*)qws;         // 8-byte fp8 frags
    const long* tb = (const long*)tws;

    // A fragments: a[rt][ks] = A[row0+rt*16+l15][k = ks*32 + quad*8 + j]
    // long-unit offset: row*32 + ks*4 + quad
    long a[8][8];
#pragma unroll
    for (int rt = 0; rt < 8; ++rt) {
        const int base = (row0 + rt * 16 + l15) * 32 + quad;
#pragma unroll
        for (int ks = 0; ks < 8; ++ks)
            a[rt][ks] = qa[base + ks * 4];
    }

    f32x4 rowacc[8];
#pragma unroll
    for (int rt = 0; rt < 8; ++rt) rowacc[rt] = f32x4{0.f, 0.f, 0.f, 0.f};
    float diagacc = 0.f;

    // prefetch strip 0's B frags
    long bq[8];
    {
        const int bb = (col0 + l15) * 32 + quad;
#pragma unroll
        for (int ks = 0; ks < 8; ++ks) bq[ks] = tb[bb + ks * 4];
    }

    for (int strip = 0; strip < 16; ++strip) {
        long bn[8];
        if (strip + 1 < 16) {
            const int bb = (col0 + (strip + 1) * 16 + l15) * 32 + quad;
#pragma unroll
            for (int ks = 0; ks < 8; ++ks) bn[ks] = tb[bb + ks * 4];
        }

        f32x4 acc[8];
#pragma unroll
        for (int rt = 0; rt < 8; ++rt) acc[rt] = f32x4{0.f, 0.f, 0.f, 0.f};
#pragma unroll
        for (int ks = 0; ks < 8; ++ks)
#pragma unroll
            for (int rt = 0; rt < 8; ++rt)
                acc[rt] = __builtin_amdgcn_mfma_f32_16x16x32_fp8_fp8(
                    a[rt][ks], bq[ks], acc[rt], 0, 0, 0);

        // epilogue: exp2-sum per row (exp2(K2*(d-1)) == exp((d-1)/T))
#pragma unroll
        for (int rt = 0; rt < 8; ++rt)
#pragma unroll
            for (int i = 0; i < 4; ++i)
                rowacc[rt][i] += exp2f(fmaf(acc[rt][i], K2, -K2));

        // diagonal: wave-uniform per (strip, rt); at most one rt matches
        const int c0s = col0 + strip * 16;
        if (c0s >= row0 && c0s < row0 + 128 && ((c0s - row0) & 15) == 0) {
            const int rt = (c0s - row0) >> 4;
#pragma unroll
            for (int i = 0; i < 4; ++i)
                if (l15 == quad * 4 + i) diagacc += acc[rt][i] * INV_T;
        }

#pragma unroll
        for (int ks = 0; ks < 8; ++ks) bq[ks] = bn[ks];
    }

    // reduce row partials across the 16 l15 lanes -> atomics (32 rows/wave)
#pragma unroll
    for (int rt = 0; rt < 8; ++rt)
#pragma unroll
        for (int i = 0; i < 4; ++i) {
            float s = rowacc[rt][i];
            s += __shfl_xor(s, 1, 64);
            s += __shfl_xor(s, 2, 64);
            s += __shfl_xor(s, 4, 64);
            s += __shfl_xor(s, 8, 64);
            if (l15 == 0)
                atomicAdd(&rowsum[row0 + rt * 16 + quad * 4 + i], s);
        }

    float dsum = diagacc;
#pragma unroll
    for (int off = 32; off; off >>= 1) dsum += __shfl_xor(dsum, off, 64);
    if (lane == 0 && dsum != 0.f) atomicAdd(diagsum, dsum);

    // ticket: last block computes the loss
    __syncthreads();
    if (tid == 0) {
        __threadfence();
        int old = __hip_atomic_fetch_add(ticket, 1, __ATOMIC_ACQ_REL,
                                         __HIP_MEMORY_SCOPE_AGENT);
        lastflag = (old == GRID_GEMM - 1);
    }
    __syncthreads();
    if (!lastflag) return;

    float lsum = 0.f;
    for (int rr = tid; rr < B_DIM; rr += 256) {
        float rv = __hip_atomic_load(&rowsum[rr], __ATOMIC_RELAXED,
                                     __HIP_MEMORY_SCOPE_AGENT);
        lsum += __logf(rv);
    }
#pragma unroll
    for (int off = 32; off; off >>= 1) lsum += __shfl_xor(lsum, off, 64);
    if (lane == 0) wred[w] = lsum;
    __syncthreads();
    if (tid == 0) {
        float ds = __hip_atomic_load(diagsum, __ATOMIC_RELAXED,
                                     __HIP_MEMORY_SCOPE_AGENT);
        float total = wred[0] + wred[1] + wred[2] + wred[3]
                    + (float)B_DIM * INV_T   // + M per row
                    - ds;                    // - positive logits
        out[0] = total / (float)B_DIM;
    }
}

extern "C" void kernel_launch(void* const* d_in, const int* in_sizes, int n_in,
                              void* d_out, int out_size, void* d_ws, size_t ws_size,
                              hipStream_t stream)
{
    const float* h = (const float*)d_in[0];
    const float* r = (const float*)d_in[1];
    const float* t = (const float*)d_in[2];

    unsigned char* ws = (unsigned char*)d_ws;
    unsigned int* qws = (unsigned int*)ws;                            // 2 MB fp8
    unsigned int* tws = (unsigned int*)(ws + 2u * 1024 * 1024);       // 2 MB fp8
    float* rowsum  = (float*)(ws + 4u * 1024 * 1024);                 // 32 KB
    float* diagsum = (float*)(ws + 4u * 1024 * 1024 + 32768u);
    int*   ticket  = (int*)  (ws + 4u * 1024 * 1024 + 32768u + 4);

    norm_kernel<<<4096, 256, 0, stream>>>(h, r, t, qws, tws, rowsum, diagsum, ticket);
    gemm_lse_kernel<<<GRID_GEMM, 256, 0, stream>>>(
        (const unsigned char*)qws, (const unsigned char*)tws,
        rowsum, diagsum, ticket, (float*)d_out);
}